// Round 2
// baseline (431.936 us; speedup 1.0000x reference)
//
#include <hip/hip_runtime.h>
#include <math.h>

#define NEURONS 8192
#define BATCH_N 2048

// Correctly-rounded-f32-exp based sigmoid, mimicking numpy f32 op sequence:
// p = fl32( 1 / fl32( 1 + fl32(exp(-z)) ) )
__device__ __forceinline__ float ref_sigmoid(float z) {
    double e = exp(-(double)z);          // f64 exp, <=1 ulp -> rounds to CR f32 exp
    float ef = (float)e;
    return __fdiv_rn(1.0f, __fadd_rn(1.0f, ef));
}

// K1: per-neuron LIF membrane recurrence over the batch dimension.
// One thread per neuron (8192 threads). Exact f32 op order of the reference:
//   v = v + alpha * (-v + i)   (no FMA contraction)
__global__ __launch_bounds__(256) void lif_v_kernel(const float* __restrict__ I,
                                                    const float* __restrict__ V0,
                                                    float* __restrict__ V) {
    int j = blockIdx.x * 256 + threadIdx.x;
    const float alpha = 0.05f;            // fl32(1.0/20.0), matches reference
    float v = V0[j];
    size_t idx = (size_t)j;
    #pragma unroll 8
    for (int t = 0; t < BATCH_N; ++t) {
        float iv = I[idx];
        v = __fadd_rn(v, __fmul_rn(alpha, __fadd_rn(iv, -v)));
        V[idx] = v;
        idx += NEURONS;
    }
}

// K2: autoregressive Bernoulli scan along neurons, one wave per batch row.
// Binary-state recurrence: s_i = s_{i-1} ? s1_i : s0_i with
//   s0 = (u < sigmoid(v)), s1 = (u < sigmoid(v+0.5)).
// Each map is constant (s0==s1) or identity (s0=0,s1=1); resolved via 64-bit
// ballots: s_i = value of last constant lane <= i, else carry-in.
// Reads V in place from VS and overwrites with spikes (read-before-write per wave).
__global__ __launch_bounds__(256) void spike_kernel(const float* __restrict__ U,
                                                    float* __restrict__ VS) {
    int gtid = blockIdx.x * 256 + threadIdx.x;
    int wave = gtid >> 6;                  // 0..2047, exactly BATCH_N waves
    int lane = gtid & 63;
    const size_t row = (size_t)wave * NEURONS;
    const float* u_row = U + row;
    float* vs_row = VS + row;

    int carry = 0;                         // prev_spike starts at 0 each row
    for (int c = 0; c < NEURONS; c += 256) {   // 256 neurons per chunk (4/lane)
        int base = c + lane * 4;
        float4 v4 = *reinterpret_cast<const float4*>(vs_row + base);
        float4 u4 = *reinterpret_cast<const float4*>(u_row + base);
        float vv[4] = {v4.x, v4.y, v4.z, v4.w};
        float uu[4] = {u4.x, u4.y, u4.z, u4.w};

        int s0[4], s1[4];
        #pragma unroll
        for (int k = 0; k < 4; ++k) {
            float p0 = ref_sigmoid(vv[k]);
            float p1 = ref_sigmoid(__fadd_rn(vv[k], 0.5f));
            s0[k] = (uu[k] < p0) ? 1 : 0;
            s1[k] = (uu[k] < p1) ? 1 : 0;
        }

        // Compose this lane's 4 maps into one {0,1}->{0,1} map (st0, st1).
        int st0 = 0, st1 = 1;
        #pragma unroll
        for (int k = 0; k < 4; ++k) {
            st0 = st0 ? s1[k] : s0[k];
            st1 = st1 ? s1[k] : s0[k];
        }

        unsigned long long constMask = __ballot(st0 == st1);   // constant maps
        unsigned long long valMask   = __ballot(st0 != 0);     // their value
        unsigned long long below = constMask &
            ((lane == 0) ? 0ull : (~0ull >> (64 - lane)));     // strictly below
        int cin = below ? (int)((valMask >> (63 - __clzll(below))) & 1ull)
                        : carry;

        // Apply the 4 in-lane maps sequentially from the resolved carry-in.
        int s = cin;
        float out[4];
        #pragma unroll
        for (int k = 0; k < 4; ++k) {
            s = s ? s1[k] : s0[k];
            out[k] = (float)s;
        }
        *reinterpret_cast<float4*>(vs_row + base) =
            make_float4(out[0], out[1], out[2], out[3]);

        // carry for next chunk = final state after lane 63's elements
        carry = __shfl(s, 63);
    }
}

extern "C" void kernel_launch(void* const* d_in, const int* in_sizes, int n_in,
                              void* d_out, int out_size, void* d_ws, size_t ws_size,
                              hipStream_t stream) {
    const float* I  = (const float*)d_in[0];   // input_current (2048, 8192) f32
    const float* U  = (const float*)d_in[1];   // u             (2048, 8192) f32
    const float* V0 = (const float*)d_in[2];   // v0            (8192,)      f32
    float* OUT = (float*)d_out;                // spikes (2048, 8192) f32; also V scratch

    (void)in_sizes; (void)n_in; (void)out_size; (void)d_ws; (void)ws_size;

    // K1: V into d_out (it is exactly BATCH_N*NEURONS floats)
    lif_v_kernel<<<NEURONS / 256, 256, 0, stream>>>(I, V0, OUT);
    // K2: one wave per row; 2048 waves = 512 blocks * 4 waves
    spike_kernel<<<(BATCH_N * 64) / 256, 256, 0, stream>>>(U, OUT);
}

// Round 3
// 248.190 us; speedup vs baseline: 1.7403x; 1.7403x over previous
//
#include <hip/hip_runtime.h>

#define NEURONS 8192
#define BATCH_N 2048

// Inline branch-free f64 exp, then replicate numpy's f32 op sequence:
// ef = fl32(exp(-(f64)z)); p = fl32(1 / fl32(1 + ef)).
// Inputs here satisfy |z| <= ~3 (v is a contracting AR accumulation), so no
// overflow/subnormal handling needed. Cody-Waite + degree-13 Taylor Horner:
// poly truncation ~6e-18 rel, rounding ~1e-16 rel -> f32 rounding identical
// to libm exp except within ~2^-48 of a boundary (expected flips ~1e-7 total).
__device__ __forceinline__ float ref_sigmoid(float zf) {
    double z = -(double)zf;
    const double LOG2E  = 1.4426950408889634074;
    const double LN2_HI = 6.93147180369123816490e-01;
    const double LN2_LO = 1.90821492927058770002e-10;
    double kd = __builtin_rint(z * LOG2E);
    double r  = __builtin_fma(-kd, LN2_HI, z);
    r         = __builtin_fma(-kd, LN2_LO, r);
    double p;
    p = 1.6059043836821613e-10;                 // 1/13!
    p = __builtin_fma(p, r, 2.0876756987868099e-09);   // 1/12!
    p = __builtin_fma(p, r, 2.5052108385441720e-08);   // 1/11!
    p = __builtin_fma(p, r, 2.7557319223985893e-07);   // 1/10!
    p = __builtin_fma(p, r, 2.7557319223985893e-06);   // 1/9!
    p = __builtin_fma(p, r, 2.4801587301587302e-05);   // 1/8!
    p = __builtin_fma(p, r, 1.9841269841269841e-04);   // 1/7!
    p = __builtin_fma(p, r, 1.3888888888888889e-03);   // 1/6!
    p = __builtin_fma(p, r, 8.3333333333333333e-03);   // 1/5!
    p = __builtin_fma(p, r, 4.1666666666666664e-02);   // 1/4!
    p = __builtin_fma(p, r, 1.6666666666666666e-01);   // 1/3!
    p = __builtin_fma(p, r, 5.0e-01);                  // 1/2!
    p = __builtin_fma(p, r, 1.0);
    p = __builtin_fma(p, r, 1.0);
    long long ki = (long long)kd;
    double two_k = __longlong_as_double((unsigned long long)(ki + 1023) << 52);
    float ef = (float)(p * two_k);
    return __fdiv_rn(1.0f, __fadd_rn(1.0f, ef));
}

// K1: per-neuron LIF membrane recurrence over batch. Exact f32 op order:
//   v = v + alpha * (i - v)   via __fadd_rn/__fmul_rn (no FMA contraction).
// 128 blocks x 64 threads (one wave/block, 128 CUs) + double-buffered groups
// of 32 rows -> ~64 outstanding loads/wave (~vmcnt cap) for latency hiding.
#define GROUP 32
__global__ __launch_bounds__(64) void lif_v_kernel(const float* __restrict__ I,
                                                   const float* __restrict__ V0,
                                                   float* __restrict__ V) {
    int j = blockIdx.x * 64 + threadIdx.x;
    const float alpha = 0.05f;
    float v = V0[j];
    const float* ip = I + j;
    float* vp = V + j;
    float buf0[GROUP], buf1[GROUP];

    #pragma unroll
    for (int k = 0; k < GROUP; ++k) buf0[k] = ip[(size_t)k * NEURONS];

    const int NGROUPS = BATCH_N / GROUP;   // 64
    for (int g = 0; g < NGROUPS; g += 2) {
        // prefetch group g+1
        {
            const float* p = ip + (size_t)(g + 1) * GROUP * NEURONS;
            #pragma unroll
            for (int k = 0; k < GROUP; ++k) buf1[k] = p[(size_t)k * NEURONS];
        }
        // compute group g
        {
            float* q = vp + (size_t)g * GROUP * NEURONS;
            #pragma unroll
            for (int k = 0; k < GROUP; ++k) {
                v = __fadd_rn(v, __fmul_rn(alpha, __fadd_rn(buf0[k], -v)));
                q[(size_t)k * NEURONS] = v;
            }
        }
        // prefetch group g+2
        if (g + 2 < NGROUPS) {
            const float* p = ip + (size_t)(g + 2) * GROUP * NEURONS;
            #pragma unroll
            for (int k = 0; k < GROUP; ++k) buf0[k] = p[(size_t)k * NEURONS];
        }
        // compute group g+1
        {
            float* q = vp + (size_t)(g + 1) * GROUP * NEURONS;
            #pragma unroll
            for (int k = 0; k < GROUP; ++k) {
                v = __fadd_rn(v, __fmul_rn(alpha, __fadd_rn(buf1[k], -v)));
                q[(size_t)k * NEURONS] = v;
            }
        }
    }
}

// K2: autoregressive Bernoulli scan, one wave per batch row, ballot-resolved.
// s0 = (u < sigmoid(v)), s1 = (u < sigmoid(fl(v+0.5))); each neuron is a
// monotone {0,1}->{0,1} map (constant or identity); carry resolved per 256-
// neuron chunk via 64-bit ballots. Chunk loads double-buffered in registers.
__global__ __launch_bounds__(256) void spike_kernel(const float* __restrict__ U,
                                                    float* __restrict__ VS) {
    int gtid = blockIdx.x * 256 + threadIdx.x;
    int wave = gtid >> 6;                  // 0..2047
    int lane = gtid & 63;
    const size_t row = (size_t)wave * NEURONS;
    const float* u_row = U + row;
    float* vs_row = VS + row;

    float4 cv = *reinterpret_cast<const float4*>(vs_row + lane * 4);
    float4 cu = *reinterpret_cast<const float4*>(u_row + lane * 4);

    int carry = 0;
    for (int c = 0; c < NEURONS; c += 256) {
        int base = c + lane * 4;
        // prefetch next chunk (clamped reload of current on last iter; those
        // loads issue before this chunk's store, values discarded)
        int nbase = (c + 256 < NEURONS) ? (base + 256) : base;
        float4 nv = *reinterpret_cast<const float4*>(vs_row + nbase);
        float4 nu = *reinterpret_cast<const float4*>(u_row + nbase);

        float vv[4] = {cv.x, cv.y, cv.z, cv.w};
        float uu[4] = {cu.x, cu.y, cu.z, cu.w};

        int s0[4], s1[4];
        #pragma unroll
        for (int k = 0; k < 4; ++k) {
            float p0 = ref_sigmoid(vv[k]);
            float p1 = ref_sigmoid(__fadd_rn(vv[k], 0.5f));
            s0[k] = (uu[k] < p0) ? 1 : 0;
            s1[k] = (uu[k] < p1) ? 1 : 0;
        }

        int st0 = 0, st1 = 1;
        #pragma unroll
        for (int k = 0; k < 4; ++k) {
            st0 = st0 ? s1[k] : s0[k];
            st1 = st1 ? s1[k] : s0[k];
        }

        unsigned long long constMask = __ballot(st0 == st1);
        unsigned long long valMask   = __ballot(st0 != 0);
        unsigned long long below = constMask &
            ((lane == 0) ? 0ull : (~0ull >> (64 - lane)));
        int cin = below ? (int)((valMask >> (63 - __clzll(below))) & 1ull)
                        : carry;

        int s = cin;
        float out[4];
        #pragma unroll
        for (int k = 0; k < 4; ++k) {
            s = s ? s1[k] : s0[k];
            out[k] = (float)s;
        }
        *reinterpret_cast<float4*>(vs_row + base) =
            make_float4(out[0], out[1], out[2], out[3]);

        carry = __shfl(s, 63);
        cv = nv; cu = nu;
    }
}

extern "C" void kernel_launch(void* const* d_in, const int* in_sizes, int n_in,
                              void* d_out, int out_size, void* d_ws, size_t ws_size,
                              hipStream_t stream) {
    const float* I  = (const float*)d_in[0];   // input_current (2048, 8192) f32
    const float* U  = (const float*)d_in[1];   // u             (2048, 8192) f32
    const float* V0 = (const float*)d_in[2];   // v0            (8192,)      f32
    float* OUT = (float*)d_out;                // spikes; also V scratch (in-place)

    (void)in_sizes; (void)n_in; (void)out_size; (void)d_ws; (void)ws_size;

    lif_v_kernel<<<NEURONS / 64, 64, 0, stream>>>(I, V0, OUT);
    spike_kernel<<<(BATCH_N * 64) / 256, 256, 0, stream>>>(U, OUT);
}

// Round 4
// 214.129 us; speedup vs baseline: 2.0172x; 1.1591x over previous
//
#include <hip/hip_runtime.h>

#define NEURONS 8192
#define BATCH_N 2048
#define GROUP 32          // rows per load group (double-buffered)
#define CHUNK_ROWS 512    // batch rows per parallel chunk
#define WARMUP 512        // warmup rows for chunks > 0 (0.95^512 ~ 4e-12 -> trajectories merge)

// Inline branch-free f64 exp, then replicate numpy's f32 op sequence:
// ef = fl32(exp(-(f64)z)); p = fl32(1 / fl32(1 + ef)).
// |z| <= ~3 here (v is a contracting AR accumulation), so k in [-5,5]:
// no overflow/subnormal handling. Cody-Waite + degree-10 Taylor Horner:
// truncation (r<=0.347) ~7e-12 rel -> P(f32 rounding differs from libm)
// ~6e-5 per exp is wrong by 1 ulp of p; expected spike flips ~1e-4 total.
__device__ __forceinline__ float ref_sigmoid(float zf) {
    double z = -(double)zf;
    const double LOG2E  = 1.4426950408889634074;
    const double LN2_HI = 6.93147180369123816490e-01;
    const double LN2_LO = 1.90821492927058770002e-10;
    double kd = __builtin_rint(z * LOG2E);
    double r  = __builtin_fma(-kd, LN2_HI, z);
    r         = __builtin_fma(-kd, LN2_LO, r);
    double p;
    p = 2.7557319223985888e-07;                        // 1/10!
    p = __builtin_fma(p, r, 2.7557319223985893e-06);   // 1/9!
    p = __builtin_fma(p, r, 2.4801587301587302e-05);   // 1/8!
    p = __builtin_fma(p, r, 1.9841269841269841e-04);   // 1/7!
    p = __builtin_fma(p, r, 1.3888888888888889e-03);   // 1/6!
    p = __builtin_fma(p, r, 8.3333333333333332e-03);   // 1/5!
    p = __builtin_fma(p, r, 4.1666666666666664e-02);   // 1/4!
    p = __builtin_fma(p, r, 1.6666666666666666e-01);   // 1/3!
    p = __builtin_fma(p, r, 5.0e-01);                  // 1/2!
    p = __builtin_fma(p, r, 1.0);
    p = __builtin_fma(p, r, 1.0);
    long long ki = (long long)kd;
    double two_k = __longlong_as_double((unsigned long long)(ki + 1023) << 52);
    float ef = (float)(p * two_k);
    return __fdiv_rn(1.0f, __fadd_rn(1.0f, ef));
}

// One 512-row span of the LIF recurrence, double-buffered in GROUP=32 row
// groups. Exact f32 op order: v = v + alpha*(i - v), no FMA contraction.
// STORE=false is the warmup replay (loads only, state converges to the
// reference trajectory).
template <bool STORE>
__device__ __forceinline__ float lif_span(const float* __restrict__ ip,
                                          float* __restrict__ vp, float v) {
    const float alpha = 0.05f;
    float buf0[GROUP], buf1[GROUP];
    #pragma unroll
    for (int k = 0; k < GROUP; ++k) buf0[k] = ip[(size_t)k * NEURONS];

    const int NGROUPS = CHUNK_ROWS / GROUP;   // 16, even
    for (int g = 0; g < NGROUPS; g += 2) {
        {   // prefetch group g+1
            const float* p = ip + (size_t)(g + 1) * GROUP * NEURONS;
            #pragma unroll
            for (int k = 0; k < GROUP; ++k) buf1[k] = p[(size_t)k * NEURONS];
        }
        {   // compute group g
            float* q = vp + (size_t)g * GROUP * NEURONS;
            #pragma unroll
            for (int k = 0; k < GROUP; ++k) {
                v = __fadd_rn(v, __fmul_rn(alpha, __fadd_rn(buf0[k], -v)));
                if constexpr (STORE) q[(size_t)k * NEURONS] = v;
            }
        }
        if (g + 2 < NGROUPS) {   // prefetch group g+2
            const float* p = ip + (size_t)(g + 2) * GROUP * NEURONS;
            #pragma unroll
            for (int k = 0; k < GROUP; ++k) buf0[k] = p[(size_t)k * NEURONS];
        }
        {   // compute group g+1
            float* q = vp + (size_t)(g + 1) * GROUP * NEURONS;
            #pragma unroll
            for (int k = 0; k < GROUP; ++k) {
                v = __fadd_rn(v, __fmul_rn(alpha, __fadd_rn(buf1[k], -v)));
                if constexpr (STORE) q[(size_t)k * NEURONS] = v;
            }
        }
    }
    return v;
}

// K1: LIF membrane recurrence, batch-parallelized into 4 chunks of 512 rows.
// Chunks 1..3 warm up on the preceding 512 rows (no stores) starting from V0;
// the contracting f32 iteration merges onto the exact reference trajectory.
// 512 blocks x 64 threads -> 512 waves, ~4 MB in flight.
__global__ __launch_bounds__(64) void lif_v_kernel(const float* __restrict__ I,
                                                   const float* __restrict__ V0,
                                                   float* __restrict__ V) {
    int nb    = blockIdx.x & 127;        // neuron block (128 x 64 = 8192)
    int chunk = blockIdx.x >> 7;         // 0..3
    int j = nb * 64 + (int)threadIdx.x;
    float v = V0[j];
    int row0 = chunk * CHUNK_ROWS;
    if (chunk > 0) {
        const float* ip = I + (size_t)(row0 - WARMUP) * NEURONS + j;
        v = lif_span<false>(ip, nullptr, v);
    }
    const float* ip = I + (size_t)row0 * NEURONS + j;
    float*       vp = V + (size_t)row0 * NEURONS + j;
    lif_span<true>(ip, vp, v);
}

// K2: autoregressive Bernoulli scan, one wave per batch row, ballot-resolved.
// s0 = (u < sigmoid(v)), s1 = (u < sigmoid(fl(v+0.5))); each neuron is a
// monotone {0,1}->{0,1} map (constant or identity); carry resolved per 256-
// neuron chunk via 64-bit ballots. Chunk loads double-buffered in registers.
__global__ __launch_bounds__(256) void spike_kernel(const float* __restrict__ U,
                                                    float* __restrict__ VS) {
    int gtid = blockIdx.x * 256 + threadIdx.x;
    int wave = gtid >> 6;                  // 0..2047
    int lane = gtid & 63;
    const size_t row = (size_t)wave * NEURONS;
    const float* u_row = U + row;
    float* vs_row = VS + row;
    const unsigned long long ltmask =
        (lane == 0) ? 0ull : (~0ull >> (64 - lane));   // lanes strictly below

    float4 cv = *reinterpret_cast<const float4*>(vs_row + lane * 4);
    float4 cu = *reinterpret_cast<const float4*>(u_row + lane * 4);

    int carry = 0;
    for (int c = 0; c < NEURONS; c += 256) {
        int base = c + lane * 4;
        // prefetch next chunk (clamped reload on last iter; discarded)
        int nbase = (c + 256 < NEURONS) ? (base + 256) : base;
        float4 nv = *reinterpret_cast<const float4*>(vs_row + nbase);
        float4 nu = *reinterpret_cast<const float4*>(u_row + nbase);

        float vv[4] = {cv.x, cv.y, cv.z, cv.w};
        float uu[4] = {cu.x, cu.y, cu.z, cu.w};

        int s0[4], s1[4];
        #pragma unroll
        for (int k = 0; k < 4; ++k) {
            float p0 = ref_sigmoid(vv[k]);
            float p1 = ref_sigmoid(__fadd_rn(vv[k], 0.5f));
            s0[k] = (uu[k] < p0) ? 1 : 0;
            s1[k] = (uu[k] < p1) ? 1 : 0;
        }

        int st0 = 0, st1 = 1;
        #pragma unroll
        for (int k = 0; k < 4; ++k) {
            st0 = st0 ? s1[k] : s0[k];
            st1 = st1 ? s1[k] : s0[k];
        }

        unsigned long long constMask = __ballot(st0 == st1);
        unsigned long long valMask   = __ballot(st0 != 0);
        unsigned long long below = constMask & ltmask;
        int cin = below ? (int)((valMask >> (63 - __clzll(below))) & 1ull)
                        : carry;

        int s = cin;
        float out[4];
        #pragma unroll
        for (int k = 0; k < 4; ++k) {
            s = s ? s1[k] : s0[k];
            out[k] = (float)s;
        }
        *reinterpret_cast<float4*>(vs_row + base) =
            make_float4(out[0], out[1], out[2], out[3]);

        carry = __shfl(s, 63);
        cv = nv; cu = nu;
    }
}

extern "C" void kernel_launch(void* const* d_in, const int* in_sizes, int n_in,
                              void* d_out, int out_size, void* d_ws, size_t ws_size,
                              hipStream_t stream) {
    const float* I  = (const float*)d_in[0];   // input_current (2048, 8192) f32
    const float* U  = (const float*)d_in[1];   // u             (2048, 8192) f32
    const float* V0 = (const float*)d_in[2];   // v0            (8192,)      f32
    float* OUT = (float*)d_out;                // spikes; also V scratch (in-place)

    (void)in_sizes; (void)n_in; (void)out_size; (void)d_ws; (void)ws_size;

    // K1: 4 batch-chunks x 128 neuron-blocks = 512 blocks x 64 threads
    lif_v_kernel<<<512, 64, 0, stream>>>(I, V0, OUT);
    // K2: one wave per row; 2048 waves = 512 blocks x 4 waves
    spike_kernel<<<(BATCH_N * 64) / 256, 256, 0, stream>>>(U, OUT);
}

// Round 5
// 212.382 us; speedup vs baseline: 2.0338x; 1.0082x over previous
//
#include <hip/hip_runtime.h>

#define NEURONS 8192
#define BATCH_N 2048
#define GROUP 32          // rows per load group in K1 (double-buffered)
#define CHUNK_ROWS 512    // batch rows per parallel chunk in K1
#define WARMUP 512        // warmup rows for chunks > 0 (0.95^512 ~ 4e-12)
#define SEG 2048          // neurons per wave in K2 (4 waves x 2048 = 8192)

// Inline branch-free f64 exp, then replicate numpy's f32 op sequence:
// ef = fl32(exp(-(f64)z)); p = fl32(1 / fl32(1 + ef)).
// |z| <= ~3 here, so k in [-5,5]: no overflow/subnormal handling.
// Cody-Waite + degree-10 Taylor Horner: truncation ~2e-13 rel ->
// P(f32 rounding differs from libm exp) ~4e-6/exp, and a last-ulp ef change
// only flips a spike if u lands in that ~6e-8 window -> expected flips ~1e-8.
__device__ __forceinline__ float ref_sigmoid(float zf) {
    double z = -(double)zf;
    const double LOG2E  = 1.4426950408889634074;
    const double LN2_HI = 6.93147180369123816490e-01;
    const double LN2_LO = 1.90821492927058770002e-10;
    double kd = __builtin_rint(z * LOG2E);
    double r  = __builtin_fma(-kd, LN2_HI, z);
    r         = __builtin_fma(-kd, LN2_LO, r);
    double p;
    p = 2.7557319223985888e-07;                        // 1/10!
    p = __builtin_fma(p, r, 2.7557319223985893e-06);   // 1/9!
    p = __builtin_fma(p, r, 2.4801587301587302e-05);   // 1/8!
    p = __builtin_fma(p, r, 1.9841269841269841e-04);   // 1/7!
    p = __builtin_fma(p, r, 1.3888888888888889e-03);   // 1/6!
    p = __builtin_fma(p, r, 8.3333333333333332e-03);   // 1/5!
    p = __builtin_fma(p, r, 4.1666666666666664e-02);   // 1/4!
    p = __builtin_fma(p, r, 1.6666666666666666e-01);   // 1/3!
    p = __builtin_fma(p, r, 5.0e-01);                  // 1/2!
    p = __builtin_fma(p, r, 1.0);
    p = __builtin_fma(p, r, 1.0);
    long long ki = (long long)kd;
    double two_k = __longlong_as_double((unsigned long long)(ki + 1023) << 52);
    float ef = (float)(p * two_k);
    return __fdiv_rn(1.0f, __fadd_rn(1.0f, ef));
}

// One 512-row span of the LIF recurrence, double-buffered in GROUP=32 row
// groups. Exact f32 op order: v = v + alpha*(i - v), no FMA contraction.
template <bool STORE>
__device__ __forceinline__ float lif_span(const float* __restrict__ ip,
                                          float* __restrict__ vp, float v) {
    const float alpha = 0.05f;
    float buf0[GROUP], buf1[GROUP];
    #pragma unroll
    for (int k = 0; k < GROUP; ++k) buf0[k] = ip[(size_t)k * NEURONS];

    const int NGROUPS = CHUNK_ROWS / GROUP;   // 16, even
    for (int g = 0; g < NGROUPS; g += 2) {
        {   // prefetch group g+1
            const float* p = ip + (size_t)(g + 1) * GROUP * NEURONS;
            #pragma unroll
            for (int k = 0; k < GROUP; ++k) buf1[k] = p[(size_t)k * NEURONS];
        }
        {   // compute group g
            float* q = vp + (size_t)g * GROUP * NEURONS;
            #pragma unroll
            for (int k = 0; k < GROUP; ++k) {
                v = __fadd_rn(v, __fmul_rn(alpha, __fadd_rn(buf0[k], -v)));
                if constexpr (STORE) q[(size_t)k * NEURONS] = v;
            }
        }
        if (g + 2 < NGROUPS) {   // prefetch group g+2
            const float* p = ip + (size_t)(g + 2) * GROUP * NEURONS;
            #pragma unroll
            for (int k = 0; k < GROUP; ++k) buf0[k] = p[(size_t)k * NEURONS];
        }
        {   // compute group g+1
            float* q = vp + (size_t)(g + 1) * GROUP * NEURONS;
            #pragma unroll
            for (int k = 0; k < GROUP; ++k) {
                v = __fadd_rn(v, __fmul_rn(alpha, __fadd_rn(buf1[k], -v)));
                if constexpr (STORE) q[(size_t)k * NEURONS] = v;
            }
        }
    }
    return v;
}

// K1: LIF membrane recurrence, batch-parallelized into 4 chunks of 512 rows.
// Chunks 1..3 warm up on the preceding 512 rows (no stores) from V0; the
// contracting f32 iteration (x0.95/step -> 4e-12) merges exactly onto the
// reference trajectory (rounding shadowing).
__global__ __launch_bounds__(64) void lif_v_kernel(const float* __restrict__ I,
                                                   const float* __restrict__ V0,
                                                   float* __restrict__ V) {
    int nb    = blockIdx.x & 127;        // neuron block (128 x 64 = 8192)
    int chunk = blockIdx.x >> 7;         // 0..3
    int j = nb * 64 + (int)threadIdx.x;
    float v = V0[j];
    int row0 = chunk * CHUNK_ROWS;
    if (chunk > 0) {
        const float* ip = I + (size_t)(row0 - WARMUP) * NEURONS + j;
        v = lif_span<false>(ip, nullptr, v);
    }
    const float* ip = I + (size_t)row0 * NEURONS + j;
    float*       vp = V + (size_t)row0 * NEURONS + j;
    lif_span<true>(ip, vp, v);
}

// K2: autoregressive Bernoulli scan. One block (4 waves) per row; wave w owns
// neurons [w*SEG, (w+1)*SEG). Each wave computes BOTH candidate output
// bit-sequences (segment carry-in 0 and 1) in a single pass over 8 chunks of
// 256 neurons, tracking per-chunk start states under both hypotheses.
// Per-chunk carry resolution within the wave uses the monotone-map ballot
// trick: s0 = (u < sigmoid(v)), s1 = (u < sigmoid(fl(v+0.5))); constant maps
// (s0==s1) pin the state, identity maps pass it through.
// Segment maps meet in LDS; one barrier; each wave selects its bitmask and
// expands to float4 stores. Selection logic is bit-exact vs the serial scan.
__global__ __launch_bounds__(256) void spike_kernel(const float* __restrict__ U,
                                                    float* __restrict__ VS) {
    __shared__ int m0s[4], m1s[4];
    int row  = blockIdx.x;
    int wid  = threadIdx.x >> 6;          // 0..3
    int lane = threadIdx.x & 63;
    const size_t rbase = (size_t)row * NEURONS;
    const float* u_seg = U  + rbase + wid * SEG;
    float*      vs_seg = VS + rbase + wid * SEG;
    const unsigned long long ltmask =
        (lane == 0) ? 0ull : (~0ull >> (64 - lane));   // lanes strictly below

    float4 cv = *reinterpret_cast<const float4*>(vs_seg + lane * 4);
    float4 cu = *reinterpret_cast<const float4*>(u_seg + lane * 4);

    unsigned int out_a = 0, out_b = 0;    // outputs under seg-carry-in 0 / 1
    int a = 0, b = 1;                      // chunk-start states, both hyps
    #pragma unroll
    for (int c8 = 0; c8 < 8; ++c8) {
        int base  = c8 * 256 + lane * 4;
        int nbase = (c8 < 7) ? (base + 256) : base;   // clamped prefetch
        float4 nv = *reinterpret_cast<const float4*>(vs_seg + nbase);
        float4 nu = *reinterpret_cast<const float4*>(u_seg + nbase);

        float vv[4] = {cv.x, cv.y, cv.z, cv.w};
        float uu[4] = {cu.x, cu.y, cu.z, cu.w};

        int s0[4], s1[4];
        #pragma unroll
        for (int k = 0; k < 4; ++k) {
            float p0 = ref_sigmoid(vv[k]);
            float p1 = ref_sigmoid(__fadd_rn(vv[k], 0.5f));
            s0[k] = (uu[k] < p0) ? 1 : 0;
            s1[k] = (uu[k] < p1) ? 1 : 0;
        }

        // per-lane composed map over 4 neurons
        int st0 = 0, st1 = 1;
        #pragma unroll
        for (int k = 0; k < 4; ++k) {
            st0 = st0 ? s1[k] : s0[k];
            st1 = st1 ? s1[k] : s0[k];
        }

        unsigned long long constMask = __ballot(st0 == st1);
        unsigned long long valMask   = __ballot(st0 != 0);
        unsigned long long below     = constMask & ltmask;
        int vb  = below ? (int)((valMask >> (63 - __clzll(below))) & 1ull) : 0;
        int has = below ? 1 : 0;
        int cin0 = has ? vb : 0;          // lane carry-in if chunk starts at 0
        int cin1 = has ? vb : 1;          // ... if chunk starts at 1

        int sA = cin0, sB = cin1;
        unsigned int o0 = 0, o1 = 0;      // lane's 4 outputs, both chunk hyps
        #pragma unroll
        for (int k = 0; k < 4; ++k) {
            sA = sA ? s1[k] : s0[k];  o0 |= (unsigned)sA << k;
            sB = sB ? s1[k] : s0[k];  o1 |= (unsigned)sB << k;
        }
        int t0 = __shfl(sA, 63);          // chunk map applied to 0
        int t1 = __shfl(sB, 63);          // chunk map applied to 1

        out_a |= (a ? o1 : o0) << (4 * c8);
        out_b |= (b ? o1 : o0) << (4 * c8);
        a = a ? t1 : t0;
        b = b ? t1 : t0;
        cv = nv; cu = nu;
    }

    if (lane == 0) { m0s[wid] = a; m1s[wid] = b; }
    __syncthreads();
    int cin = 0;                          // row starts with prev_spike = 0
    for (int i = 0; i < wid; ++i) cin = cin ? m1s[i] : m0s[i];
    unsigned int bits = cin ? out_b : out_a;

    #pragma unroll
    for (int c8 = 0; c8 < 8; ++c8) {
        unsigned int nib = bits >> (4 * c8);
        *reinterpret_cast<float4*>(vs_seg + c8 * 256 + lane * 4) =
            make_float4((float)(nib & 1), (float)((nib >> 1) & 1),
                        (float)((nib >> 2) & 1), (float)((nib >> 3) & 1));
    }
}

extern "C" void kernel_launch(void* const* d_in, const int* in_sizes, int n_in,
                              void* d_out, int out_size, void* d_ws, size_t ws_size,
                              hipStream_t stream) {
    const float* I  = (const float*)d_in[0];   // input_current (2048, 8192) f32
    const float* U  = (const float*)d_in[1];   // u             (2048, 8192) f32
    const float* V0 = (const float*)d_in[2];   // v0            (8192,)      f32
    float* OUT = (float*)d_out;                // spikes; also V scratch (in-place)

    (void)in_sizes; (void)n_in; (void)out_size; (void)d_ws; (void)ws_size;

    // K1: 4 batch-chunks x 128 neuron-blocks = 512 blocks x 64 threads
    lif_v_kernel<<<512, 64, 0, stream>>>(I, V0, OUT);
    // K2: one block (4 waves) per batch row
    spike_kernel<<<BATCH_N, 256, 0, stream>>>(U, OUT);
}

// Round 6
// 198.206 us; speedup vs baseline: 2.1792x; 1.0715x over previous
//
#include <hip/hip_runtime.h>

#define NEURONS 8192
#define BATCH_N 2048
#define GROUP 32          // rows per load group in K1 (double-buffered)
#define CHUNK_ROWS 512    // batch rows per parallel chunk in K1
#define WARMUP 512        // warmup rows for chunks > 0 (0.95^512 ~ 4e-12)
#define SEG 2048          // neurons per wave in K2 (4 waves x 2048 = 8192)

// EXACT path (validated rounds 2-5, absmax 0.0): inline branch-free f64 exp,
// then numpy's f32 op sequence: ef = fl32(exp(-(f64)z)); p = fl32(1/fl32(1+ef)).
__device__ __forceinline__ float ref_sigmoid(float zf) {
    double z = -(double)zf;
    const double LOG2E  = 1.4426950408889634074;
    const double LN2_HI = 6.93147180369123816490e-01;
    const double LN2_LO = 1.90821492927058770002e-10;
    double kd = __builtin_rint(z * LOG2E);
    double r  = __builtin_fma(-kd, LN2_HI, z);
    r         = __builtin_fma(-kd, LN2_LO, r);
    double p;
    p = 2.7557319223985888e-07;                        // 1/10!
    p = __builtin_fma(p, r, 2.7557319223985893e-06);   // 1/9!
    p = __builtin_fma(p, r, 2.4801587301587302e-05);   // 1/8!
    p = __builtin_fma(p, r, 1.9841269841269841e-04);   // 1/7!
    p = __builtin_fma(p, r, 1.3888888888888889e-03);   // 1/6!
    p = __builtin_fma(p, r, 8.3333333333333332e-03);   // 1/5!
    p = __builtin_fma(p, r, 4.1666666666666664e-02);   // 1/4!
    p = __builtin_fma(p, r, 1.6666666666666666e-01);   // 1/3!
    p = __builtin_fma(p, r, 5.0e-01);                  // 1/2!
    p = __builtin_fma(p, r, 1.0);
    p = __builtin_fma(p, r, 1.0);
    long long ki = (long long)kd;
    double two_k = __longlong_as_double((unsigned long long)(ki + 1023) << 52);
    float ef = (float)(p * two_k);
    return __fdiv_rn(1.0f, __fadd_rn(1.0f, ef));
}

// One 512-row span of the LIF recurrence, double-buffered in GROUP=32 row
// groups. Exact f32 op order: v = v + alpha*(i - v), no FMA contraction.
template <bool STORE>
__device__ __forceinline__ float lif_span(const float* __restrict__ ip,
                                          float* __restrict__ vp, float v) {
    const float alpha = 0.05f;
    float buf0[GROUP], buf1[GROUP];
    #pragma unroll
    for (int k = 0; k < GROUP; ++k) buf0[k] = ip[(size_t)k * NEURONS];

    const int NGROUPS = CHUNK_ROWS / GROUP;   // 16, even
    for (int g = 0; g < NGROUPS; g += 2) {
        {   // prefetch group g+1
            const float* p = ip + (size_t)(g + 1) * GROUP * NEURONS;
            #pragma unroll
            for (int k = 0; k < GROUP; ++k) buf1[k] = p[(size_t)k * NEURONS];
        }
        {   // compute group g
            float* q = vp + (size_t)g * GROUP * NEURONS;
            #pragma unroll
            for (int k = 0; k < GROUP; ++k) {
                v = __fadd_rn(v, __fmul_rn(alpha, __fadd_rn(buf0[k], -v)));
                if constexpr (STORE) q[(size_t)k * NEURONS] = v;
            }
        }
        if (g + 2 < NGROUPS) {   // prefetch group g+2
            const float* p = ip + (size_t)(g + 2) * GROUP * NEURONS;
            #pragma unroll
            for (int k = 0; k < GROUP; ++k) buf0[k] = p[(size_t)k * NEURONS];
        }
        {   // compute group g+1
            float* q = vp + (size_t)(g + 1) * GROUP * NEURONS;
            #pragma unroll
            for (int k = 0; k < GROUP; ++k) {
                v = __fadd_rn(v, __fmul_rn(alpha, __fadd_rn(buf1[k], -v)));
                if constexpr (STORE) q[(size_t)k * NEURONS] = v;
            }
        }
    }
    return v;
}

// K1: LIF membrane recurrence, batch-parallelized into 4 chunks of 512 rows.
// Chunks 1..3 warm up on the preceding 512 rows (no stores) from V0; the
// contracting f32 iteration (x0.95/step -> 4e-12) merges exactly onto the
// reference trajectory (rounding shadowing; validated absmax 0.0).
__global__ __launch_bounds__(64) void lif_v_kernel(const float* __restrict__ I,
                                                   const float* __restrict__ V0,
                                                   float* __restrict__ V) {
    int nb    = blockIdx.x & 127;        // neuron block (128 x 64 = 8192)
    int chunk = blockIdx.x >> 7;         // 0..3
    int j = nb * 64 + (int)threadIdx.x;
    float v = V0[j];
    int row0 = chunk * CHUNK_ROWS;
    if (chunk > 0) {
        const float* ip = I + (size_t)(row0 - WARMUP) * NEURONS + j;
        v = lif_span<false>(ip, nullptr, v);
    }
    const float* ip = I + (size_t)row0 * NEURONS + j;
    float*       vp = V + (size_t)row0 * NEURONS + j;
    lif_span<true>(ip, vp, v);
}

// K2: autoregressive Bernoulli scan, one block (4 waves) per row, each wave
// owning 2048 neurons, dual carry hypotheses (validated round 5).
//
// NEW: fast f32 certificate for the spike bit. The reference decision
// u < fl32(1/fl32(1+ef)) is equivalent to sign(u*(1+e)-1) except within
// ~1.2e-7 of the boundary. We evaluate q = fma(u, e~, u-1) with
// e~ = exp2(-v*log2e) via hardware v_exp_f32 (<=1 ulp) [e1~ = e0~*e^-0.5].
// Total proxy error < ~5e-7; margin M=4e-6 (>=8x slack). |q| > M decides the
// bit provably identically to the reference; |q| <= M (P ~ 5e-6/compare,
// ~1e2 wave-occurrences per kernel) falls back to the exact f64 path.
__global__ __launch_bounds__(256) void spike_kernel(const float* __restrict__ U,
                                                    float* __restrict__ VS) {
    __shared__ int m0s[4], m1s[4];
    int row  = blockIdx.x;
    int wid  = threadIdx.x >> 6;          // 0..3
    int lane = threadIdx.x & 63;
    const size_t rbase = (size_t)row * NEURONS;
    const float* u_seg = U  + rbase + wid * SEG;
    float*      vs_seg = VS + rbase + wid * SEG;
    const unsigned long long ltmask =
        (lane == 0) ? 0ull : (~0ull >> (64 - lane));   // lanes strictly below

    const float NLOG2E = -1.4426950408889634f;  // -log2(e), f32-rounded
    const float EHALF  = 0.60653065971263342f;  // e^-0.5, f32-rounded
    const float M      = 4e-6f;                 // certificate margin

    float4 cv = *reinterpret_cast<const float4*>(vs_seg + lane * 4);
    float4 cu = *reinterpret_cast<const float4*>(u_seg + lane * 4);

    unsigned int out_a = 0, out_b = 0;    // outputs under seg-carry-in 0 / 1
    int a = 0, b = 1;                      // chunk-start states, both hyps
    #pragma unroll
    for (int c8 = 0; c8 < 8; ++c8) {
        int base  = c8 * 256 + lane * 4;
        int nbase = (c8 < 7) ? (base + 256) : base;   // clamped prefetch
        float4 nv = *reinterpret_cast<const float4*>(vs_seg + nbase);
        float4 nu = *reinterpret_cast<const float4*>(u_seg + nbase);

        float vv[4] = {cv.x, cv.y, cv.z, cv.w};
        float uu[4] = {cu.x, cu.y, cu.z, cu.w};

        int s0[4], s1[4];
        int amb = 0;
        #pragma unroll
        for (int k = 0; k < 4; ++k) {
            float t  = vv[k] * NLOG2E;                   // -v*log2e
            float e0 = __builtin_amdgcn_exp2f(t);        // ~exp(-v)
            float e1 = e0 * EHALF;                       // ~exp(-(v+0.5))
            float um1 = uu[k] - 1.0f;
            float q0 = fmaf(uu[k], e0, um1);             // u*(1+e0) - 1
            float q1 = fmaf(uu[k], e1, um1);
            s0[k] = (q0 < 0.0f) ? 1 : 0;
            s1[k] = (q1 < 0.0f) ? 1 : 0;
            amb |= (fabsf(q0) <= M) | (fabsf(q1) <= M);
        }
        if (__any(amb)) {                 // rare: exact recompute, whole wave
            #pragma unroll
            for (int k = 0; k < 4; ++k) {
                s0[k] = (uu[k] < ref_sigmoid(vv[k])) ? 1 : 0;
                s1[k] = (uu[k] < ref_sigmoid(__fadd_rn(vv[k], 0.5f))) ? 1 : 0;
            }
        }

        // per-lane composed map over 4 neurons
        int st0 = 0, st1 = 1;
        #pragma unroll
        for (int k = 0; k < 4; ++k) {
            st0 = st0 ? s1[k] : s0[k];
            st1 = st1 ? s1[k] : s0[k];
        }

        unsigned long long constMask = __ballot(st0 == st1);
        unsigned long long valMask   = __ballot(st0 != 0);
        unsigned long long below     = constMask & ltmask;
        int vb  = below ? (int)((valMask >> (63 - __clzll(below))) & 1ull) : 0;
        int has = below ? 1 : 0;
        int cin0 = has ? vb : 0;          // lane carry-in if chunk starts at 0
        int cin1 = has ? vb : 1;          // ... if chunk starts at 1

        int sA = cin0, sB = cin1;
        unsigned int o0 = 0, o1 = 0;      // lane's 4 outputs, both chunk hyps
        #pragma unroll
        for (int k = 0; k < 4; ++k) {
            sA = sA ? s1[k] : s0[k];  o0 |= (unsigned)sA << k;
            sB = sB ? s1[k] : s0[k];  o1 |= (unsigned)sB << k;
        }
        int t0 = __shfl(sA, 63);          // chunk map applied to 0
        int t1 = __shfl(sB, 63);          // chunk map applied to 1

        out_a |= (a ? o1 : o0) << (4 * c8);
        out_b |= (b ? o1 : o0) << (4 * c8);
        a = a ? t1 : t0;
        b = b ? t1 : t0;
        cv = nv; cu = nu;
    }

    if (lane == 0) { m0s[wid] = a; m1s[wid] = b; }
    __syncthreads();
    int cin = 0;                          // row starts with prev_spike = 0
    for (int i = 0; i < wid; ++i) cin = cin ? m1s[i] : m0s[i];
    unsigned int bits = cin ? out_b : out_a;

    #pragma unroll
    for (int c8 = 0; c8 < 8; ++c8) {
        unsigned int nib = bits >> (4 * c8);
        *reinterpret_cast<float4*>(vs_seg + c8 * 256 + lane * 4) =
            make_float4((float)(nib & 1), (float)((nib >> 1) & 1),
                        (float)((nib >> 2) & 1), (float)((nib >> 3) & 1));
    }
}

extern "C" void kernel_launch(void* const* d_in, const int* in_sizes, int n_in,
                              void* d_out, int out_size, void* d_ws, size_t ws_size,
                              hipStream_t stream) {
    const float* I  = (const float*)d_in[0];   // input_current (2048, 8192) f32
    const float* U  = (const float*)d_in[1];   // u             (2048, 8192) f32
    const float* V0 = (const float*)d_in[2];   // v0            (8192,)      f32
    float* OUT = (float*)d_out;                // spikes; also V scratch (in-place)

    (void)in_sizes; (void)n_in; (void)out_size; (void)d_ws; (void)ws_size;

    // K1: 4 batch-chunks x 128 neuron-blocks = 512 blocks x 64 threads
    lif_v_kernel<<<512, 64, 0, stream>>>(I, V0, OUT);
    // K2: one block (4 waves) per batch row
    spike_kernel<<<BATCH_N, 256, 0, stream>>>(U, OUT);
}